// Round 3
// baseline (635.646 us; speedup 1.0000x reference)
//
#include <hip/hip_runtime.h>

#define HID 64
#define IN_CH 128

// ---------- bf16 helpers (RNE) ----------
__device__ __forceinline__ float bf2f(unsigned short u) {
    return __uint_as_float((unsigned)u << 16);
}
__device__ __forceinline__ unsigned short f2bf(float f) {
    unsigned u = __float_as_uint(f);
    unsigned r = u + 0x7FFFu + ((u >> 16) & 1u);
    return (unsigned short)(r >> 16);
}

// ============ CSR build: histogram -> scan -> scatter ============

__global__ __launch_bounds__(256) void hist_kernel(const int* __restrict__ dst,
                                                   int* __restrict__ cnt, int E) {
    int e = blockIdx.x * 256 + threadIdx.x;
    if (e < E) atomicAdd(&cnt[dst[e]], 1);
}

__global__ __launch_bounds__(256) void block_sum_kernel(const int* __restrict__ cnt,
                                                        int* __restrict__ bsum, int N) {
    int i = blockIdx.x * 256 + threadIdx.x;
    int v = (i < N) ? cnt[i] : 0;
#pragma unroll
    for (int m = 1; m < 64; m <<= 1) v += __shfl_xor(v, m);
    __shared__ int wsm[4];
    if ((threadIdx.x & 63) == 0) wsm[threadIdx.x >> 6] = v;
    __syncthreads();
    if (threadIdx.x == 0) bsum[blockIdx.x] = wsm[0] + wsm[1] + wsm[2] + wsm[3];
}

__global__ __launch_bounds__(512) void scan_bsum_kernel(int* __restrict__ bsum,
                                                        int* __restrict__ off,
                                                        int NB, int N, int E) {
    __shared__ int sm[512];
    __shared__ int carry;
    const int t = threadIdx.x;
    if (t == 0) carry = 0;
    __syncthreads();
    for (int base = 0; base < NB; base += 512) {
        const int idx = base + t;
        const int v = (idx < NB) ? bsum[idx] : 0;
        sm[t] = v;
        __syncthreads();
        for (int d = 1; d < 512; d <<= 1) {
            int x = sm[t];
            int y = (t >= d) ? sm[t - d] : 0;
            __syncthreads();
            sm[t] = x + y;
            __syncthreads();
        }
        if (idx < NB) bsum[idx] = carry + sm[t] - v;
        __syncthreads();
        if (t == 0) carry += sm[511];
        __syncthreads();
    }
    if (t == 0) off[N] = E;
}

__global__ __launch_bounds__(256) void block_scan_kernel(const int* __restrict__ cnt,
                                                         const int* __restrict__ bsum,
                                                         int* __restrict__ off, int N) {
    __shared__ int sm[256];
    const int i = blockIdx.x * 256 + threadIdx.x;
    const int t = threadIdx.x;
    const int v = (i < N) ? cnt[i] : 0;
    sm[t] = v;
    __syncthreads();
    for (int d = 1; d < 256; d <<= 1) {
        int x = sm[t];
        int y = (t >= d) ? sm[t - d] : 0;
        __syncthreads();
        sm[t] = x + y;
        __syncthreads();
    }
    if (i < N) off[i] = bsum[blockIdx.x] + sm[t] - v;  // exclusive
}

__global__ __launch_bounds__(256) void dinv_kernel(const int* __restrict__ cnt,
                                                   float* __restrict__ dinv, int N) {
    int i = blockIdx.x * 256 + threadIdx.x;
    if (i < N) dinv[i] = rsqrtf((float)cnt[i] + 1.0f);  // +1 self-loop
}

// packed edge record: .x = src node, .y = float bits of dinv[s]*dinv[d]
__global__ __launch_bounds__(256) void scatter_kernel(
    const int* __restrict__ src, const int* __restrict__ dst,
    const int* __restrict__ off, int* __restrict__ pos,
    const float* __restrict__ dinv, int2* __restrict__ epk, int E) {
    int e = blockIdx.x * 256 + threadIdx.x;
    if (e < E) {
        const int d = dst[e];
        const int s = src[e];
        const int p = off[d] + atomicAdd(&pos[d], 1);
        int2 r;
        r.x = s;
        r.y = __float_as_int(dinv[s] * dinv[d]);
        epk[p] = r;
    }
}

// ============ GEMM: Bout = A[N,K] @ W[K,64] (+bias), fp32 or bf16 out =====
template <int K, int ROWS, bool ADD_BIAS, bool OUT_BF16>
__global__ __launch_bounds__(256) void gemm_kernel(
    const float* __restrict__ A, const float* __restrict__ W,
    const float* __restrict__ bias, void* __restrict__ Bout, int N) {
    constexpr int PAD = 4;
    constexpr int RT = ROWS / 16;
    __shared__ float ws[K * HID];
    __shared__ float as[ROWS * (K + PAD)];

    const int tid = threadIdx.x;
    const int row_base = blockIdx.x * ROWS;

    for (int i = tid; i < K * HID; i += 256) ws[i] = W[i];
    for (int i = tid; i < ROWS * K; i += 256) {
        int r = i / K, k = i - r * K;
        int gr = row_base + r;
        as[r * (K + PAD) + k] = (gr < N) ? A[(size_t)gr * K + k] : 0.0f;
    }
    __syncthreads();

    const int tx = tid & 15, ty = tid >> 4;
    const int c0 = tx * 4, r0 = ty * RT;

    float acc[RT][4];
#pragma unroll
    for (int j = 0; j < RT; j++)
#pragma unroll
        for (int i2 = 0; i2 < 4; i2++) acc[j][i2] = 0.0f;

    for (int k = 0; k < K; k += 4) {
        float4 av[RT], wv[4];
#pragma unroll
        for (int j = 0; j < RT; j++)
            av[j] = *(const float4*)&as[(r0 + j) * (K + PAD) + k];
#pragma unroll
        for (int kk = 0; kk < 4; kk++)
            wv[kk] = *(const float4*)&ws[(k + kk) * HID + c0];
#pragma unroll
        for (int j = 0; j < RT; j++) {
#pragma unroll
            for (int kk = 0; kk < 4; kk++) {
                const float a = (&av[j].x)[kk];
                acc[j][0] += a * wv[kk].x;
                acc[j][1] += a * wv[kk].y;
                acc[j][2] += a * wv[kk].z;
                acc[j][3] += a * wv[kk].w;
            }
        }
    }

#pragma unroll
    for (int j = 0; j < RT; j++) {
        const int gr = row_base + r0 + j;
        if (gr < N) {
            float4 v = make_float4(acc[j][0], acc[j][1], acc[j][2], acc[j][3]);
            if (ADD_BIAS) {
                const float4 bv = *(const float4*)&bias[c0];
                v.x += bv.x; v.y += bv.y; v.z += bv.z; v.w += bv.w;
            }
            const size_t o = (size_t)gr * HID + c0;
            if (OUT_BF16) {
                ushort4 s4;
                s4.x = f2bf(v.x); s4.y = f2bf(v.y);
                s4.z = f2bf(v.z); s4.w = f2bf(v.w);
                *(ushort4*)((unsigned short*)Bout + o) = s4;
            } else {
                *(float4*)((float*)Bout + o) = v;
            }
        }
    }
}

// ============ fused aggregate + LayerNorm (+relu+residual) ============
// one wave per node, lane = channel, hw in bf16, edges packed (src, norm).
// LAST=false: res = relu(LN(acc)) + res ; LAST=true: out = LN(acc)
template <bool LAST>
__global__ __launch_bounds__(256) void agg_ln_kernel(
    const int* __restrict__ off, const int2* __restrict__ epk,
    const float* __restrict__ dinv, const unsigned short* __restrict__ hw,
    const float* __restrict__ bias, const float* __restrict__ g,
    const float* __restrict__ beta, float* __restrict__ res,
    float* __restrict__ out, int N) {
    const int row = blockIdx.x * 4 + (threadIdx.x >> 6);
    if (row >= N) return;
    const int c = threadIdx.x & 63;
    const size_t o = (size_t)row * HID + c;

    const float di = dinv[row];
    float acc0 = bias[c] + bf2f(hw[o]) * di * di;
    float acc1 = 0.0f, acc2 = 0.0f, acc3 = 0.0f;

    int p = off[row];
    const int p1 = off[row + 1];
    for (; p + 4 <= p1; p += 4) {
        const int2 e0 = epk[p];
        const int2 e1 = epk[p + 1];
        const int2 e2 = epk[p + 2];
        const int2 e3 = epk[p + 3];
        const float h0 = bf2f(hw[(size_t)e0.x * HID + c]);
        const float h1 = bf2f(hw[(size_t)e1.x * HID + c]);
        const float h2 = bf2f(hw[(size_t)e2.x * HID + c]);
        const float h3 = bf2f(hw[(size_t)e3.x * HID + c]);
        acc0 += h0 * __int_as_float(e0.y);
        acc1 += h1 * __int_as_float(e1.y);
        acc2 += h2 * __int_as_float(e2.y);
        acc3 += h3 * __int_as_float(e3.y);
    }
    for (; p < p1; ++p) {
        const int2 e = epk[p];
        acc0 += bf2f(hw[(size_t)e.x * HID + c]) * __int_as_float(e.y);
    }
    float acc = (acc0 + acc1) + (acc2 + acc3);

    // LayerNorm over 64 channels (one wave)
    float su = acc;
#pragma unroll
    for (int m = 1; m < 64; m <<= 1) su += __shfl_xor(su, m);
    const float mean = su * (1.0f / 64.0f);
    const float d = acc - mean;
    float q = d * d;
#pragma unroll
    for (int m = 1; m < 64; m <<= 1) q += __shfl_xor(q, m);
    const float var = q * (1.0f / 64.0f);
    const float y = d * rsqrtf(var + 1e-5f) * g[c] + beta[c];

    if (LAST) {
        out[o] = y;
    } else {
        res[o] = fmaxf(y, 0.0f) + res[o];
    }
}

extern "C" void kernel_launch(void* const* d_in, const int* in_sizes, int n_in,
                              void* d_out, int out_size, void* d_ws, size_t ws_size,
                              hipStream_t stream) {
    const float* x      = (const float*)d_in[0];
    const int*   ei     = (const int*)d_in[1];
    const float* proj_w = (const float*)d_in[2];
    const float* proj_b = (const float*)d_in[3];
    const float* w[3]  = {(const float*)d_in[4], (const float*)d_in[8],  (const float*)d_in[12]};
    const float* b[3]  = {(const float*)d_in[5], (const float*)d_in[9],  (const float*)d_in[13]};
    const float* g[3]  = {(const float*)d_in[6], (const float*)d_in[10], (const float*)d_in[14]};
    const float* be[3] = {(const float*)d_in[7], (const float*)d_in[11], (const float*)d_in[15]};

    const int N = in_sizes[0] / IN_CH;
    const int E = in_sizes[1] / 2;
    const int* src = ei;
    const int* dst = ei + E;
    const int NB = (N + 255) / 256;

    char* wsb = (char*)d_ws;
    size_t o2 = 0;
    auto alloc = [&](size_t bytes) {
        void* p = wsb + o2;
        o2 = (o2 + bytes + 255) & ~(size_t)255;
        return p;
    };
    int*   cnt   = (int*)alloc((size_t)N * 4);
    int*   pos   = (int*)alloc((size_t)N * 4);
    int*   off   = (int*)alloc((size_t)(N + 1) * 4);
    int*   bsum  = (int*)alloc((size_t)NB * 4);
    float* dinv  = (float*)alloc((size_t)N * 4);
    int2*  epk   = (int2*)alloc((size_t)E * 8);
    float* Abuf  = (float*)alloc((size_t)N * HID * 4);           // h / residual (fp32)
    unsigned short* Bbuf = (unsigned short*)alloc((size_t)N * HID * 2);  // hw (bf16)

    // ---- CSR build ----
    hipMemsetAsync(cnt, 0, (size_t)N * 4, stream);
    hipMemsetAsync(pos, 0, (size_t)N * 4, stream);
    hist_kernel<<<(E + 255) / 256, 256, 0, stream>>>(dst, cnt, E);
    block_sum_kernel<<<NB, 256, 0, stream>>>(cnt, bsum, N);
    scan_bsum_kernel<<<1, 512, 0, stream>>>(bsum, off, NB, N, E);
    block_scan_kernel<<<NB, 256, 0, stream>>>(cnt, bsum, off, N);
    dinv_kernel<<<(N + 255) / 256, 256, 0, stream>>>(cnt, dinv, N);
    scatter_kernel<<<(E + 255) / 256, 256, 0, stream>>>(src, dst, off, pos, dinv,
                                                        epk, E);

    // ---- input projection: A = x @ proj_w + proj_b (fp32 out) ----
    gemm_kernel<IN_CH, 32, true, false><<<(N + 31) / 32, 256, 0, stream>>>(
        x, proj_w, proj_b, Abuf, N);

    // ---- 3 GCN layers ----
    for (int l = 0; l < 3; l++) {
        gemm_kernel<HID, 64, false, true><<<(N + 63) / 64, 256, 0, stream>>>(
            Abuf, w[l], nullptr, Bbuf, N);
        if (l < 2) {
            agg_ln_kernel<false><<<(N + 3) / 4, 256, 0, stream>>>(
                off, epk, dinv, Bbuf, b[l], g[l], be[l], Abuf, nullptr, N);
        } else {
            agg_ln_kernel<true><<<(N + 3) / 4, 256, 0, stream>>>(
                off, epk, dinv, Bbuf, b[l], g[l], be[l], nullptr,
                (float*)d_out, N);
        }
    }
}

// Round 4
// 455.267 us; speedup vs baseline: 1.3962x; 1.3962x over previous
//
#include <hip/hip_runtime.h>

#define HID 64
#define IN_CH 128

typedef __attribute__((ext_vector_type(8))) short bf16x8;
typedef __attribute__((ext_vector_type(4))) float f32x4;

// ---------- bf16 helpers (RNE) ----------
__device__ __forceinline__ float bf2f(unsigned short u) {
    return __uint_as_float((unsigned)u << 16);
}
__device__ __forceinline__ unsigned short f2bf(float f) {
    unsigned u = __float_as_uint(f);
    unsigned r = u + 0x7FFFu + ((u >> 16) & 1u);
    return (unsigned short)(r >> 16);
}

// ============ CSR build: histogram -> scan -> scatter ============

__global__ __launch_bounds__(256) void hist_kernel(const int* __restrict__ dst,
                                                   int* __restrict__ cnt, int E) {
    int e = blockIdx.x * 256 + threadIdx.x;
    if (e < E) atomicAdd(&cnt[dst[e]], 1);
}

__global__ __launch_bounds__(256) void block_sum_kernel(const int* __restrict__ cnt,
                                                        int* __restrict__ bsum, int N) {
    int i = blockIdx.x * 256 + threadIdx.x;
    int v = (i < N) ? cnt[i] : 0;
#pragma unroll
    for (int m = 1; m < 64; m <<= 1) v += __shfl_xor(v, m);
    __shared__ int wsm[4];
    if ((threadIdx.x & 63) == 0) wsm[threadIdx.x >> 6] = v;
    __syncthreads();
    if (threadIdx.x == 0) bsum[blockIdx.x] = wsm[0] + wsm[1] + wsm[2] + wsm[3];
}

__global__ __launch_bounds__(512) void scan_bsum_kernel(int* __restrict__ bsum,
                                                        int* __restrict__ off,
                                                        int NB, int N, int E) {
    __shared__ int sm[512];
    __shared__ int carry;
    const int t = threadIdx.x;
    if (t == 0) carry = 0;
    __syncthreads();
    for (int base = 0; base < NB; base += 512) {
        const int idx = base + t;
        const int v = (idx < NB) ? bsum[idx] : 0;
        sm[t] = v;
        __syncthreads();
        for (int d = 1; d < 512; d <<= 1) {
            int x = sm[t];
            int y = (t >= d) ? sm[t - d] : 0;
            __syncthreads();
            sm[t] = x + y;
            __syncthreads();
        }
        if (idx < NB) bsum[idx] = carry + sm[t] - v;
        __syncthreads();
        if (t == 0) carry += sm[511];
        __syncthreads();
    }
    if (t == 0) off[N] = E;
}

__global__ __launch_bounds__(256) void block_scan_kernel(const int* __restrict__ cnt,
                                                         const int* __restrict__ bsum,
                                                         int* __restrict__ off, int N) {
    __shared__ int sm[256];
    const int i = blockIdx.x * 256 + threadIdx.x;
    const int t = threadIdx.x;
    const int v = (i < N) ? cnt[i] : 0;
    sm[t] = v;
    __syncthreads();
    for (int d = 1; d < 256; d <<= 1) {
        int x = sm[t];
        int y = (t >= d) ? sm[t - d] : 0;
        __syncthreads();
        sm[t] = x + y;
        __syncthreads();
    }
    if (i < N) off[i] = bsum[blockIdx.x] + sm[t] - v;  // exclusive
}

__global__ __launch_bounds__(256) void dinv_kernel(const int* __restrict__ cnt,
                                                   float* __restrict__ dinv, int N) {
    int i = blockIdx.x * 256 + threadIdx.x;
    if (i < N) dinv[i] = rsqrtf((float)cnt[i] + 1.0f);  // +1 self-loop
}

// packed edge record: .x = src node, .y = float bits of dinv[s]*dinv[d]
__global__ __launch_bounds__(256) void scatter_kernel(
    const int* __restrict__ src, const int* __restrict__ dst,
    const int* __restrict__ off, int* __restrict__ pos,
    const float* __restrict__ dinv, int2* __restrict__ epk, int E) {
    int e = blockIdx.x * 256 + threadIdx.x;
    if (e < E) {
        const int d = dst[e];
        const int s = src[e];
        const int p = off[d] + atomicAdd(&pos[d], 1);
        int2 r;
        r.x = s;
        r.y = __float_as_int(dinv[s] * dinv[d]);
        epk[p] = r;
    }
}

// ============ weight prep: transpose to bf16 [n][k] ============
__global__ __launch_bounds__(256) void prep_weights_kernel(
    const float* __restrict__ pw, const float* __restrict__ w0,
    const float* __restrict__ w1, const float* __restrict__ w2,
    unsigned short* __restrict__ pwT, unsigned short* __restrict__ wT) {
    const int id = blockIdx.x;
    if (id == 0) {
        for (int i = threadIdx.x; i < IN_CH * HID; i += 256) {
            const int k = i >> 6, n = i & 63;
            pwT[n * IN_CH + k] = f2bf(pw[i]);
        }
    } else {
        const float* w = (id == 1) ? w0 : (id == 2) ? w1 : w2;
        unsigned short* o = wT + (id - 1) * HID * HID;
        for (int i = threadIdx.x; i < HID * HID; i += 256) {
            const int k = i >> 6, n = i & 63;
            o[n * HID + k] = f2bf(w[i]);
        }
    }
}

// ============ MFMA GEMM: out[N,64] = A[N,K](fp32) @ W[K,64] ============
// wT is bf16 [64][K] (n-major). One wave per 16 rows; block = 4 waves = 64 rows.
// OUT_BF16: out = bf16(A@W) ; else: out = fp32(A@W + bias)
template <int K, bool OUT_BF16>
__global__ __launch_bounds__(256) void gemm_mfma_kernel(
    const float* __restrict__ A, const unsigned short* __restrict__ wT,
    const float* __restrict__ bias, void* __restrict__ out, int N) {
    const int wave = threadIdx.x >> 6;
    const int lane = threadIdx.x & 63;
    const int quad = lane >> 4;
    const int m = lane & 15;
    const int rowbase = blockIdx.x * 64 + wave * 16;
    const int row = rowbase + m;

    f32x4 acc[4];
#pragma unroll
    for (int nt = 0; nt < 4; nt++) acc[nt] = (f32x4){0.f, 0.f, 0.f, 0.f};

#pragma unroll
    for (int ks = 0; ks < K; ks += 32) {
        union { bf16x8 v; unsigned short u[8]; } af;
        if (row < N) {
            const float4 a0 = *(const float4*)&A[(size_t)row * K + ks + quad * 8];
            const float4 a1 = *(const float4*)&A[(size_t)row * K + ks + quad * 8 + 4];
            af.u[0] = f2bf(a0.x); af.u[1] = f2bf(a0.y);
            af.u[2] = f2bf(a0.z); af.u[3] = f2bf(a0.w);
            af.u[4] = f2bf(a1.x); af.u[5] = f2bf(a1.y);
            af.u[6] = f2bf(a1.z); af.u[7] = f2bf(a1.w);
        } else {
#pragma unroll
            for (int j = 0; j < 8; j++) af.u[j] = 0;
        }
#pragma unroll
        for (int nt = 0; nt < 4; nt++) {
            const int n = nt * 16 + m;
            const bf16x8 bfrag = *(const bf16x8*)&wT[n * K + ks + quad * 8];
            acc[nt] = __builtin_amdgcn_mfma_f32_16x16x32_bf16(af.v, bfrag, acc[nt], 0, 0, 0);
        }
    }

    // C/D layout: col = nt*16 + m, row(within tile) = quad*4 + reg
#pragma unroll
    for (int nt = 0; nt < 4; nt++) {
#pragma unroll
        for (int r = 0; r < 4; r++) {
            const int orow = rowbase + quad * 4 + r;
            if (orow < N) {
                const int col = nt * 16 + m;
                const size_t o = (size_t)orow * HID + col;
                const float v = acc[nt][r];
                if (OUT_BF16) {
                    ((unsigned short*)out)[o] = f2bf(v);
                } else {
                    ((float*)out)[o] = v + bias[col];
                }
            }
        }
    }
}

// ============ fused aggregate + LayerNorm (+relu+residual) ============
template <bool LAST>
__global__ __launch_bounds__(256) void agg_ln_kernel(
    const int* __restrict__ off, const int2* __restrict__ epk,
    const float* __restrict__ dinv, const unsigned short* __restrict__ hw,
    const float* __restrict__ bias, const float* __restrict__ g,
    const float* __restrict__ beta, float* __restrict__ res,
    float* __restrict__ out, int N) {
    const int row = blockIdx.x * 4 + (threadIdx.x >> 6);
    if (row >= N) return;
    const int c = threadIdx.x & 63;
    const size_t o = (size_t)row * HID + c;

    const float di = dinv[row];
    float acc0 = bias[c] + bf2f(hw[o]) * di * di;
    float acc1 = 0.0f, acc2 = 0.0f, acc3 = 0.0f;

    int p = off[row];
    const int p1 = off[row + 1];
    for (; p + 4 <= p1; p += 4) {
        const int2 e0 = epk[p];
        const int2 e1 = epk[p + 1];
        const int2 e2 = epk[p + 2];
        const int2 e3 = epk[p + 3];
        const float h0 = bf2f(hw[(size_t)e0.x * HID + c]);
        const float h1 = bf2f(hw[(size_t)e1.x * HID + c]);
        const float h2 = bf2f(hw[(size_t)e2.x * HID + c]);
        const float h3 = bf2f(hw[(size_t)e3.x * HID + c]);
        acc0 += h0 * __int_as_float(e0.y);
        acc1 += h1 * __int_as_float(e1.y);
        acc2 += h2 * __int_as_float(e2.y);
        acc3 += h3 * __int_as_float(e3.y);
    }
    for (; p < p1; ++p) {
        const int2 e = epk[p];
        acc0 += bf2f(hw[(size_t)e.x * HID + c]) * __int_as_float(e.y);
    }
    float acc = (acc0 + acc1) + (acc2 + acc3);

    float su = acc;
#pragma unroll
    for (int m = 1; m < 64; m <<= 1) su += __shfl_xor(su, m);
    const float mean = su * (1.0f / 64.0f);
    const float d = acc - mean;
    float q = d * d;
#pragma unroll
    for (int m = 1; m < 64; m <<= 1) q += __shfl_xor(q, m);
    const float var = q * (1.0f / 64.0f);
    const float y = d * rsqrtf(var + 1e-5f) * g[c] + beta[c];

    if (LAST) {
        out[o] = y;
    } else {
        res[o] = fmaxf(y, 0.0f) + res[o];
    }
}

extern "C" void kernel_launch(void* const* d_in, const int* in_sizes, int n_in,
                              void* d_out, int out_size, void* d_ws, size_t ws_size,
                              hipStream_t stream) {
    const float* x      = (const float*)d_in[0];
    const int*   ei     = (const int*)d_in[1];
    const float* proj_w = (const float*)d_in[2];
    const float* proj_b = (const float*)d_in[3];
    const float* w[3]  = {(const float*)d_in[4], (const float*)d_in[8],  (const float*)d_in[12]};
    const float* b[3]  = {(const float*)d_in[5], (const float*)d_in[9],  (const float*)d_in[13]};
    const float* g[3]  = {(const float*)d_in[6], (const float*)d_in[10], (const float*)d_in[14]};
    const float* be[3] = {(const float*)d_in[7], (const float*)d_in[11], (const float*)d_in[15]};

    const int N = in_sizes[0] / IN_CH;
    const int E = in_sizes[1] / 2;
    const int* src = ei;
    const int* dst = ei + E;
    const int NB = (N + 255) / 256;

    char* wsb = (char*)d_ws;
    size_t o2 = 0;
    auto alloc = [&](size_t bytes) {
        void* p = wsb + o2;
        o2 = (o2 + bytes + 255) & ~(size_t)255;
        return p;
    };
    int*   cnt   = (int*)alloc((size_t)N * 4);
    int*   pos   = (int*)alloc((size_t)N * 4);
    int*   off   = (int*)alloc((size_t)(N + 1) * 4);
    int*   bsum  = (int*)alloc((size_t)NB * 4);
    float* dinv  = (float*)alloc((size_t)N * 4);
    int2*  epk   = (int2*)alloc((size_t)E * 8);
    float* Abuf  = (float*)alloc((size_t)N * HID * 4);                   // h / residual (fp32)
    unsigned short* Bbuf = (unsigned short*)alloc((size_t)N * HID * 2);  // hw (bf16)
    unsigned short* pwT  = (unsigned short*)alloc((size_t)HID * IN_CH * 2);
    unsigned short* wT   = (unsigned short*)alloc((size_t)3 * HID * HID * 2);

    // ---- CSR build ----
    hipMemsetAsync(cnt, 0, (size_t)N * 4, stream);
    hipMemsetAsync(pos, 0, (size_t)N * 4, stream);
    hist_kernel<<<(E + 255) / 256, 256, 0, stream>>>(dst, cnt, E);
    block_sum_kernel<<<NB, 256, 0, stream>>>(cnt, bsum, N);
    scan_bsum_kernel<<<1, 512, 0, stream>>>(bsum, off, NB, N, E);
    block_scan_kernel<<<NB, 256, 0, stream>>>(cnt, bsum, off, N);
    dinv_kernel<<<(N + 255) / 256, 256, 0, stream>>>(cnt, dinv, N);
    scatter_kernel<<<(E + 255) / 256, 256, 0, stream>>>(src, dst, off, pos, dinv,
                                                        epk, E);
    prep_weights_kernel<<<4, 256, 0, stream>>>(proj_w, w[0], w[1], w[2], pwT, wT);

    // ---- input projection: A = x @ proj_w + proj_b (fp32 out) ----
    gemm_mfma_kernel<IN_CH, false><<<(N + 63) / 64, 256, 0, stream>>>(
        x, pwT, proj_b, Abuf, N);

    // ---- 3 GCN layers ----
    for (int l = 0; l < 3; l++) {
        gemm_mfma_kernel<HID, true><<<(N + 63) / 64, 256, 0, stream>>>(
            Abuf, wT + (size_t)l * HID * HID, nullptr, Bbuf, N);
        if (l < 2) {
            agg_ln_kernel<false><<<(N + 3) / 4, 256, 0, stream>>>(
                off, epk, dinv, Bbuf, b[l], g[l], be[l], Abuf, nullptr, N);
        } else {
            agg_ln_kernel<true><<<(N + 3) / 4, 256, 0, stream>>>(
                off, epk, dinv, Bbuf, b[l], g[l], be[l], nullptr,
                (float*)d_out, N);
        }
    }
}